// Round 4
// baseline (432.446 us; speedup 1.0000x reference)
//
#include <hip/hip_runtime.h>
#include <hip/hip_bf16.h>
#include <type_traits>

// ---------------------------------------------------------------------------
// GCN forward, 2 layers. Round 11 (resubmit; R3 bench was an infra timeout):
// agg kernels restructured for MLP-under-64-VGPR: 32 lanes/node (8B/lane for
// H=128, 4B/lane for D=64), 16-wide masked gather bursts, epack slice staged
// in LDS per block (nodes are contiguous -> one contiguous epack range;
// CAP=512 + global fallback). Weights re-read from LDS at FMA time so e[]
// never occupies registers. Normal stores for out_x1 (gemm2 reads it),
// nt-store for terminal lsm out.
//
//  sortA1 (+weight tc): per-block LDS hist over 391 coarse buckets (dst>>8)
//  scan1/scan2/scan3G : flat exclusive scan of G[bucket][block] (76K ints)
//  sortA2             : place edges into bucket-grouped scratch (dense runs)
//  megaB (+gemm1)     : per-bucket exact sort -> offs[] + epack[]; gemm1
//  agg_f128b          : x1 = relu(sum w*sup1[src]+b1), fp32 out
//  gemm2              : sup2 = out_x1(fp32) @ W2
//  agg_f64_lsm        : out2 = log_softmax(sum w*sup2[src]+b2)
// ---------------------------------------------------------------------------

typedef unsigned short u16;
typedef unsigned char  u8;

__device__ __forceinline__ u16 f2bf(float x) {
    union { float f; unsigned u; } v; v.f = x;
    const unsigned r = v.u + 0x7FFFu + ((v.u >> 16) & 1u);   // RNE
    return (u16)(r >> 16);
}
__device__ __forceinline__ float bf2f(unsigned h) {
    union { unsigned u; float f; } v; v.u = h << 16;
    return v.f;
}
__device__ __forceinline__ float uaf(unsigned u) {
    union { unsigned u; float f; } v; v.u = u;
    return v.f;
}
__device__ __forceinline__ unsigned fau(float f) {
    union { float f; unsigned u; } v; v.f = f;
    return v.u;
}

using short8  = __attribute__((ext_vector_type(8))) short;
using float4v = __attribute__((ext_vector_type(4))) float;

#define TILE_A 8192

// ---------------- MFMA GEMM body: C[M,BNt](bf16) = A[M,K] @ BT[BNt,K]^T -----
template <typename AT, int BNt>
__device__ __forceinline__ void gemm_body(
    const int bix, const AT* __restrict__ A, const u16* __restrict__ BT,
    u16* __restrict__ C, const int M, const int K)
{
    constexpr int BMt = 128;
    constexpr int WAVES_N = BNt / 64;
    constexpr int WROWS = 4 / WAVES_N;
    constexpr int WMF = BMt / (16 * WROWS);
    constexpr int WNF = 4;

    __shared__ __align__(16) u16 As[BMt * 32];
    __shared__ __align__(16) u16 Bs[BNt * 32];

    const int tid  = threadIdx.x;
    const int lane = tid & 63;
    const int w    = tid >> 6;
    const int m0   = bix * BMt;

    const int wm = (w % WROWS) * (WMF * 16);
    const int wn = (w / WROWS) * 64;

    const int fm = lane & 15;
    const int kh = lane >> 4;

    float4v acc[WMF][WNF] = {};

    for (int k0 = 0; k0 < K; k0 += 32) {
        __syncthreads();
        if constexpr (std::is_same<AT, float>::value) {
#pragma unroll
            for (int i = 0; i < 4; ++i) {
                const int s   = i * 256 + tid;
                const int row = s >> 3;
                const int seg = s & 7;
                const int gr  = min(m0 + row, M - 1);
                const float4 v = *(const float4*)&A[(size_t)gr * K + k0 + seg * 4];
                ushort4 o;
                o.x = f2bf(v.x); o.y = f2bf(v.y); o.z = f2bf(v.z); o.w = f2bf(v.w);
                *(ushort4*)&As[row * 32 + seg * 4] = o;
            }
        } else {
#pragma unroll
            for (int i = 0; i < 2; ++i) {
                const int s   = i * 256 + tid;
                const int row = s >> 2;
                const int seg = s & 3;
                const int gr  = min(m0 + row, M - 1);
                *(uint4*)&As[row * 32 + seg * 8] =
                    *(const uint4*)&A[(size_t)gr * K + k0 + seg * 8];
            }
        }
#pragma unroll
        for (int i = 0; i < BNt * 4 / 256; ++i) {
            const int s   = i * 256 + tid;
            const int row = s >> 2;
            const int seg = s & 3;
            *(uint4*)&Bs[row * 32 + seg * 8] =
                *(const uint4*)&BT[(size_t)row * K + k0 + seg * 8];
        }
        __syncthreads();

        short8 af[WMF], bfr[WNF];
#pragma unroll
        for (int i = 0; i < WMF; ++i)
            af[i] = *(const short8*)&As[(wm + i * 16 + fm) * 32 + kh * 8];
#pragma unroll
        for (int j = 0; j < WNF; ++j)
            bfr[j] = *(const short8*)&Bs[(wn + j * 16 + fm) * 32 + kh * 8];
#pragma unroll
        for (int i = 0; i < WMF; ++i)
#pragma unroll
            for (int j = 0; j < WNF; ++j)
                acc[i][j] = __builtin_amdgcn_mfma_f32_16x16x32_bf16(
                    af[i], bfr[j], acc[i][j], 0, 0, 0);
    }

#pragma unroll
    for (int i = 0; i < WMF; ++i) {
#pragma unroll
        for (int j = 0; j < WNF; ++j) {
            const int col = wn + j * 16 + fm;
#pragma unroll
            for (int r = 0; r < 4; ++r) {
                const int row = m0 + wm + i * 16 + kh * 4 + r;
                if (row < M) C[(size_t)row * BNt + col] = f2bf(acc[i][j][r]);
            }
        }
    }
}

__global__ __launch_bounds__(256) void gemm2_k(
    const float* __restrict__ A, const u16* __restrict__ BT,
    u16* __restrict__ C, int M, int K)
{
    gemm_body<float, 64>(blockIdx.x, A, BT, C, M, K);
}

// ---------------- sort pass A1: per-block coarse histogram (+ weight tc) ----
__global__ __launch_bounds__(256) void sortA1_k(
    const int* __restrict__ dst, int* __restrict__ G, int E, int NBLK, int NB,
    const float* __restrict__ W1, u16* __restrict__ W1T, int K1, int N1,
    const float* __restrict__ W2, u16* __restrict__ W2T, int K2, int N2)
{
    const int b = blockIdx.x;
    if (b >= NBLK) {
        // weight transpose/cast role
        const int t = (b - NBLK) * 256 + threadIdx.x;
        const int tot1 = K1 * N1;
        if (t < tot1) {
            const int k = t % K1, nn = t / K1;
            W1T[(size_t)nn * K1 + k] = f2bf(W1[(size_t)k * N1 + nn]);
        } else {
            const int t2 = t - tot1;
            if (t2 < K2 * N2) {
                const int k = t2 % K2, nn = t2 / K2;
                W2T[(size_t)nn * K2 + k] = f2bf(W2[(size_t)k * N2 + nn]);
            }
        }
        return;
    }

    __shared__ int hist[512];
    for (int i = threadIdx.x; i < NB; i += 256) hist[i] = 0;
    __syncthreads();
    const int base = b * TILE_A;
#pragma unroll 4
    for (int i = 0; i < TILE_A; i += 256) {
        const int e = base + i + threadIdx.x;
        if (e < E) atomicAdd(&hist[((unsigned)dst[e]) >> 8], 1);
    }
    __syncthreads();
    for (int i = threadIdx.x; i < NB; i += 256)
        G[(size_t)i * NBLK + b] = hist[i];
}

// ---------------- scans (over flat G, length NB*NBLK) ----------------

#define SCAN_B 256
#define SCAN_I 8
#define SCAN_TILE (SCAN_B * SCAN_I)   // 2048

__global__ __launch_bounds__(SCAN_B) void scan_pass1(
    const int* __restrict__ in, int* __restrict__ out,
    int* __restrict__ blockSums, int n)
{
    __shared__ int waveSums[SCAN_B / 64];
    const int tid = threadIdx.x;
    const int lane = tid & 63;
    const int wid = tid >> 6;
    const int base = blockIdx.x * SCAN_TILE + tid * SCAN_I;

    int items[SCAN_I];
    int tsum = 0;
#pragma unroll
    for (int i = 0; i < SCAN_I; ++i) {
        const int idx = base + i;
        items[i] = (idx < n) ? in[idx] : 0;
        tsum += items[i];
    }
    int x = tsum;
#pragma unroll
    for (int o = 1; o < 64; o <<= 1) {
        const int y = __shfl_up(x, o, 64);
        if (lane >= o) x += y;
    }
    if (lane == 63) waveSums[wid] = x;
    __syncthreads();
    if (tid == 0) {
        int acc = 0;
#pragma unroll
        for (int w = 0; w < SCAN_B / 64; ++w) {
            const int t = waveSums[w]; waveSums[w] = acc; acc += t;
        }
        blockSums[blockIdx.x] = acc;
    }
    __syncthreads();
    int texcl = x - tsum + waveSums[wid];
#pragma unroll
    for (int i = 0; i < SCAN_I; ++i) {
        const int idx = base + i;
        if (idx < n) out[idx] = texcl;
        texcl += items[i];
    }
}

__global__ void scan_pass2(int* __restrict__ blockSums, int nb)
{
    const int lane = threadIdx.x;
    int run = 0;
    for (int base = 0; base < nb; base += 64) {
        const int idx = base + lane;
        const int v = (idx < nb) ? blockSums[idx] : 0;
        int x = v;
#pragma unroll
        for (int o = 1; o < 64; o <<= 1) {
            const int y = __shfl_up(x, o, 64);
            if (lane >= o) x += y;
        }
        if (idx < nb) blockSums[idx] = run + x - v;
        run += __shfl(x, 63, 64);
    }
}

__global__ __launch_bounds__(SCAN_B) void scan3G_k(
    int* __restrict__ G, const int* __restrict__ blockSums, int n,
    int* __restrict__ offs, int N, int E)
{
    const int idx = blockIdx.x * blockDim.x + threadIdx.x;
    if (idx < n) G[idx] += blockSums[idx / SCAN_TILE];
    if (idx == 0) offs[N] = E;
}

// ---------------- sort pass A2: place into bucket-grouped scratch ----------
__global__ __launch_bounds__(256) void sortA2_k(
    const int* __restrict__ src, const int* __restrict__ dst,
    const float* __restrict__ ew, const int* __restrict__ G,
    uint2* __restrict__ eps, u8* __restrict__ ldst, int E, int NBLK, int NB)
{
    const int b = blockIdx.x;
    __shared__ int cur[512];
    for (int i = threadIdx.x; i < NB; i += 256)
        cur[i] = G[(size_t)i * NBLK + b];
    __syncthreads();
    const int base = b * TILE_A;
#pragma unroll 4
    for (int i = 0; i < TILE_A; i += 256) {
        const int e = base + i + threadIdx.x;
        if (e < E) {
            const int d = dst[e];
            const int p = atomicAdd(&cur[((unsigned)d) >> 8], 1);
            eps[p]  = make_uint2((unsigned)src[e], fau(ew[e]));
            ldst[p] = (u8)(d & 255);
        }
    }
}

// ---------------- megaB: per-bucket exact sort || gemm1 ---------------------
// Block roles: b%3==0 && b/3<SB -> sort bucket b/3; else gemm1 block.
__global__ __launch_bounds__(256) void megaB_k(
    const uint2* __restrict__ eps, const u8* __restrict__ ldst,
    const int* __restrict__ G, int* __restrict__ offs,
    uint2* __restrict__ epack, int E, int NBLK, int NB, int N,
    const float* __restrict__ A, const u16* __restrict__ BT,
    u16* __restrict__ C, int M, int K, int GB)
{
    const int b = blockIdx.x;
    const int third = b / 3;
    int sort_id = -1, gemm_id = -1;
    if ((b % 3) == 0 && third < NB) sort_id = third;
    else gemm_id = b - min((b + 2) / 3, NB);

    if (gemm_id >= 0) {
        if (gemm_id < GB) gemm_body<float, 128>(gemm_id, A, BT, C, M, K);
        return;
    }

    const int tid = threadIdx.x;
    const int sb = sort_id;
    const int start = G[(size_t)sb * NBLK];
    const int endv  = (sb + 1 < NB) ? G[(size_t)(sb + 1) * NBLK] : E;

    __shared__ int h[256];
    __shared__ int wsum[4];
    h[tid] = 0;
    __syncthreads();
    for (int i = start + tid; i < endv; i += 256)
        atomicAdd(&h[ldst[i]], 1);
    __syncthreads();

    // 256-entry exclusive scan (wave shfl + 4-way combine)
    const int lane = tid & 63;
    const int w = tid >> 6;
    const int v = h[tid];
    int x = v;
#pragma unroll
    for (int o = 1; o < 64; o <<= 1) {
        const int y = __shfl_up(x, o, 64);
        if (lane >= o) x += y;
    }
    if (lane == 63) wsum[w] = x;
    __syncthreads();
    if (tid == 0) {
        int a = 0;
#pragma unroll
        for (int q = 0; q < 4; ++q) { const int t = wsum[q]; wsum[q] = a; a += t; }
    }
    __syncthreads();
    const int excl = start + (x - v) + wsum[w];

    const int node = sb * 256 + tid;
    if (node < N) offs[node] = excl;

    __syncthreads();
    h[tid] = excl;          // reuse as per-node cursor
    __syncthreads();

    for (int i = start + tid; i < endv; i += 256) {
        const uint2 ep = eps[i];
        const int p = atomicAdd(&h[ldst[i]], 1);
        epack[p] = ep;
    }
}

// ---------------- gather-side aggregation (bf16 payload) ----------------
// Round 11: 32 lanes/node, 8 nodes/block. Block's epack slice is contiguous
// (nodes sorted) -> stage into LDS (CAP=512, avg len 128, global fallback).
// 16-wide masked gather burst; weights re-read from LDS at FMA time so only
// v[16] stays live (VGPR < 64 -> 8 waves/SIMD tier).

#define AGG_CAP 512

__global__ __launch_bounds__(256) void agg_f128b(
    const u16* __restrict__ sup, const int* __restrict__ offs,
    const uint2* __restrict__ epack, const float* __restrict__ bias,
    float* __restrict__ out, int N)
{
    __shared__ uint2 se[AGG_CAP];
    const int tid = threadIdx.x;
    const int n0  = blockIdx.x * 8;
    const int nE  = min(n0 + 8, N);
    const int begB = offs[n0];
    const int endB = offs[nE];
    const int len  = endB - begB;
    for (int i = tid; i < min(len, AGG_CAP); i += 256)
        se[i] = epack[begB + i];
    __syncthreads();

    const int node = n0 + (tid >> 5);
    const int hl   = tid & 31;
    if (node >= N) return;

    const int beg = offs[node];
    const int end = offs[node + 1];

    float a[2][4] = {};
    for (int j = beg; j < end; j += 16) {
        uint2 v[16];
#pragma unroll
        for (int i = 0; i < 16; ++i) {
            const int jj = (j + i < end) ? (j + i) : (end - 1);
            const int li = jj - begB;
            const unsigned s = (li < AGG_CAP) ? se[li].x : epack[jj].x;
            v[i] = *(const uint2*)&sup[(size_t)s * 128 + hl * 4];
        }
#pragma unroll
        for (int i = 0; i < 16; ++i) {
            const int jj = j + i;
            float w = 0.f;
            if (jj < end) {
                const int li = jj - begB;
                w = (li < AGG_CAP) ? uaf(se[li].y) : uaf(epack[jj].y);
            }
            float* acc = a[i & 1];
            acc[0] = fmaf(bf2f(v[i].x & 0xffffu), w, acc[0]);
            acc[1] = fmaf(bf2f(v[i].x >> 16),     w, acc[1]);
            acc[2] = fmaf(bf2f(v[i].y & 0xffffu), w, acc[2]);
            acc[3] = fmaf(bf2f(v[i].y >> 16),     w, acc[3]);
        }
    }
    const float4 b4 = *(const float4*)&bias[hl * 4];
    float4v o0;
    o0[0] = fmaxf(a[0][0] + a[1][0] + b4.x, 0.f);
    o0[1] = fmaxf(a[0][1] + a[1][1] + b4.y, 0.f);
    o0[2] = fmaxf(a[0][2] + a[1][2] + b4.z, 0.f);
    o0[3] = fmaxf(a[0][3] + a[1][3] + b4.w, 0.f);
    *(float4v*)&out[(size_t)node * 128 + hl * 4] = o0;
}

__global__ __launch_bounds__(256) void agg_f64_lsm(
    const u16* __restrict__ sup, const int* __restrict__ offs,
    const uint2* __restrict__ epack, const float* __restrict__ bias,
    float* __restrict__ out, int N)
{
    __shared__ uint2 se[AGG_CAP];
    const int tid = threadIdx.x;
    const int n0  = blockIdx.x * 8;
    const int nE  = min(n0 + 8, N);
    const int begB = offs[n0];
    const int endB = offs[nE];
    const int len  = endB - begB;
    for (int i = tid; i < min(len, AGG_CAP); i += 256)
        se[i] = epack[begB + i];
    __syncthreads();

    const int node = n0 + (tid >> 5);
    const int hl   = tid & 31;
    if (node >= N) return;

    const int beg = offs[node];
    const int end = offs[node + 1];

    float a[2][2] = {};
    for (int j = beg; j < end; j += 16) {
        unsigned v[16];
#pragma unroll
        for (int i = 0; i < 16; ++i) {
            const int jj = (j + i < end) ? (j + i) : (end - 1);
            const int li = jj - begB;
            const unsigned s = (li < AGG_CAP) ? se[li].x : epack[jj].x;
            v[i] = *(const unsigned*)&sup[(size_t)s * 64 + hl * 2];
        }
#pragma unroll
        for (int i = 0; i < 16; ++i) {
            const int jj = j + i;
            float w = 0.f;
            if (jj < end) {
                const int li = jj - begB;
                w = (li < AGG_CAP) ? uaf(se[li].y) : uaf(epack[jj].y);
            }
            float* acc = a[i & 1];
            acc[0] = fmaf(bf2f(v[i] & 0xffffu), w, acc[0]);
            acc[1] = fmaf(bf2f(v[i] >> 16),     w, acc[1]);
        }
    }

    const float2 b2 = *(const float2*)&bias[hl * 2];
    float z0 = a[0][0] + a[1][0] + b2.x;
    float z1 = a[0][1] + a[1][1] + b2.y;

    float m = fmaxf(z0, z1);
#pragma unroll
    for (int o = 16; o > 0; o >>= 1) m = fmaxf(m, __shfl_xor(m, o, 64));
    float s = __expf(z0 - m) + __expf(z1 - m);
#pragma unroll
    for (int o = 16; o > 0; o >>= 1) s += __shfl_xor(s, o, 64);
    const float ls = __logf(s);
    using float2v = __attribute__((ext_vector_type(2))) float;
    float2v zo;
    zo[0] = z0 - m - ls;
    zo[1] = z1 - m - ls;
    __builtin_nontemporal_store(zo, (float2v*)&out[(size_t)node * 64 + hl * 2]);
}

// ---------------------------------------------------------------------------

extern "C" void kernel_launch(void* const* d_in, const int* in_sizes, int n_in,
                              void* d_out, int out_size, void* d_ws, size_t ws_size,
                              hipStream_t stream) {
    const float* feature = (const float*)d_in[0];
    const int*   src     = (const int*)d_in[1];
    const int*   dst     = (const int*)d_in[2];
    const float* ew      = (const float*)d_in[3];
    const float* W1      = (const float*)d_in[4];
    const float* b1      = (const float*)d_in[5];
    const float* W2      = (const float*)d_in[6];
    const float* b2      = (const float*)d_in[7];

    const int E    = in_sizes[1];
    const int H    = in_sizes[5];            // 128
    const int D    = in_sizes[7];            // 64
    const int F_IN = in_sizes[4] / H;        // 256
    const int N    = in_sizes[0] / F_IN;     // 100000

    float* out_x1 = (float*)d_out;                   // [N, H] fp32
    float* out_x2 = (float*)d_out + (size_t)N * H;   // [N, D] fp32

    const int NB   = (N + 255) >> 8;         // coarse buckets (391)
    const int NBLK = (E + TILE_A - 1) / TILE_A;  // A-blocks (196)
    const int nG   = NB * NBLK;              // flat G length
    const int GB   = (N + 127) / 128;        // gemm1 blocks

    char* ws = (char*)d_ws;
    auto carve = [&](size_t bytes) {
        char* p = ws;
        ws += (bytes + 15) & ~(size_t)15;
        return p;
    };
    int*   G         = (int*)  carve((size_t)nG * sizeof(int));
    int*   blockSums = (int*)  carve(4096 * sizeof(int));
    int*   offs      = (int*)  carve((size_t)(N + 1) * sizeof(int));
    uint2* epack     = (uint2*)carve((size_t)E * sizeof(uint2));
    u16*   W1T       = (u16*)  carve((size_t)H * F_IN * sizeof(u16));
    u16*   W2T       = (u16*)  carve((size_t)D * H * sizeof(u16));
    u16*   supbf     = (u16*)  carve((size_t)N * H * sizeof(u16));
    u16*   scratch   = (u16*)  carve((size_t)N * H * sizeof(u16));
    // eps/ldst scratch (dead before agg_f128b runs):
    // need E*8 + E <= N*H*2  (14.4MB <= 25.6MB) -- holds.
    uint2* eps  = (uint2*)scratch;
    u8*    ldst = (u8*)scratch + (size_t)E * sizeof(uint2);

    // --- A1: coarse histogram + weight transposes ---
    {
        const int TCB = (F_IN * H + H * D + 255) / 256;
        sortA1_k<<<NBLK + TCB, 256, 0, stream>>>(
            dst, G, E, NBLK, NB, W1, W1T, F_IN, H, W2, W2T, H, D);
    }

    // --- scan of G (flat, bucket-major) ---
    const int nScanBlocks = (nG + SCAN_TILE - 1) / SCAN_TILE;
    scan_pass1<<<nScanBlocks, SCAN_B, 0, stream>>>(G, G, blockSums, nG);
    scan_pass2<<<1, 64, 0, stream>>>(blockSums, nScanBlocks);
    scan3G_k<<<(nG + SCAN_B - 1) / SCAN_B, SCAN_B, 0, stream>>>(
        G, blockSums, nG, offs, N, E);

    // --- A2: dense bucket-grouped placement ---
    sortA2_k<<<NBLK, 256, 0, stream>>>(src, dst, ew, G, eps, ldst, E, NBLK, NB);

    // --- megaB: per-bucket exact sort || gemm1 ---
    {
        int grid = NB + GB;
        if (grid < 3 * NB - 2) grid = 3 * NB - 2;   // ensure all sort blocks exist
        megaB_k<<<grid, 256, 0, stream>>>(
            eps, ldst, G, offs, epack, E, NBLK, NB, N,
            feature, W1T, supbf, N, F_IN, GB);
    }

    // --- agg layer 1 (fused bias+relu, fp32 out) ---
    agg_f128b<<<(N + 7) / 8, 256, 0, stream>>>(
        supbf, offs, epack, b1, out_x1, N);

    // --- layer 2 (gemm2 reads fp32 out_x1 directly) ---
    gemm2_k<<<(N + 127) / 128, 256, 0, stream>>>(out_x1, W2T, supbf, N, H);
    agg_f64_lsm<<<(N + 7) / 8, 256, 0, stream>>>(
        supbf, offs, epack, b2, out_x2, N);
}

// Round 6
// 395.488 us; speedup vs baseline: 1.0934x; 1.0934x over previous
//
#include <hip/hip_runtime.h>
#include <hip/hip_bf16.h>
#include <type_traits>

// ---------------------------------------------------------------------------
// GCN forward, 2 layers. Round 13: R12 minus ALL nontemporal stores.
// R5's post-timing divergence (absmax 53.8 on x1) was nt-stores bypassing L2
// while the harness's d_out poison left dirty L2 lines -> stale readback
// (flaky, timing-dependent). Both outputs are host-read; out_x1 is also
// gemm2's input. Normal stores everywhere. Otherwise identical to the best
// measured configuration: R1 agg structure (8-wide masked bursts, 16
// lanes/node, e[] in regs) + write cut (no bf16 x1 copy; gemm2 reads fp32
// out_x1 via the float-A path).
//
//  sortA1 (+weight tc): per-block LDS hist over 391 coarse buckets (dst>>8)
//  scan1/scan2/scan3G : flat exclusive scan of G[bucket][block] (76K ints)
//  sortA2             : place edges into bucket-grouped scratch (dense runs)
//  megaB (+gemm1)     : per-bucket exact sort -> offs[] + epack[]; gemm1
//  agg_f128b          : x1 = relu(sum w*sup1[src]+b1), fp32 out
//  gemm2              : sup2 = out_x1(fp32) @ W2
//  agg_f64_lsm        : out2 = log_softmax(sum w*sup2[src]+b2)
// ---------------------------------------------------------------------------

typedef unsigned short u16;
typedef unsigned char  u8;

__device__ __forceinline__ u16 f2bf(float x) {
    union { float f; unsigned u; } v; v.f = x;
    const unsigned r = v.u + 0x7FFFu + ((v.u >> 16) & 1u);   // RNE
    return (u16)(r >> 16);
}
__device__ __forceinline__ float bf2f(unsigned h) {
    union { unsigned u; float f; } v; v.u = h << 16;
    return v.f;
}
__device__ __forceinline__ float uaf(unsigned u) {
    union { unsigned u; float f; } v; v.u = u;
    return v.f;
}
__device__ __forceinline__ unsigned fau(float f) {
    union { float f; unsigned u; } v; v.f = f;
    return v.u;
}

using short8  = __attribute__((ext_vector_type(8))) short;
using float4v = __attribute__((ext_vector_type(4))) float;

#define TILE_A 8192

// ---------------- MFMA GEMM body: C[M,BNt](bf16) = A[M,K] @ BT[BNt,K]^T -----
template <typename AT, int BNt>
__device__ __forceinline__ void gemm_body(
    const int bix, const AT* __restrict__ A, const u16* __restrict__ BT,
    u16* __restrict__ C, const int M, const int K)
{
    constexpr int BMt = 128;
    constexpr int WAVES_N = BNt / 64;
    constexpr int WROWS = 4 / WAVES_N;
    constexpr int WMF = BMt / (16 * WROWS);
    constexpr int WNF = 4;

    __shared__ __align__(16) u16 As[BMt * 32];
    __shared__ __align__(16) u16 Bs[BNt * 32];

    const int tid  = threadIdx.x;
    const int lane = tid & 63;
    const int w    = tid >> 6;
    const int m0   = bix * BMt;

    const int wm = (w % WROWS) * (WMF * 16);
    const int wn = (w / WROWS) * 64;

    const int fm = lane & 15;
    const int kh = lane >> 4;

    float4v acc[WMF][WNF] = {};

    for (int k0 = 0; k0 < K; k0 += 32) {
        __syncthreads();
        if constexpr (std::is_same<AT, float>::value) {
#pragma unroll
            for (int i = 0; i < 4; ++i) {
                const int s   = i * 256 + tid;
                const int row = s >> 3;
                const int seg = s & 7;
                const int gr  = min(m0 + row, M - 1);
                const float4 v = *(const float4*)&A[(size_t)gr * K + k0 + seg * 4];
                ushort4 o;
                o.x = f2bf(v.x); o.y = f2bf(v.y); o.z = f2bf(v.z); o.w = f2bf(v.w);
                *(ushort4*)&As[row * 32 + seg * 4] = o;
            }
        } else {
#pragma unroll
            for (int i = 0; i < 2; ++i) {
                const int s   = i * 256 + tid;
                const int row = s >> 2;
                const int seg = s & 3;
                const int gr  = min(m0 + row, M - 1);
                *(uint4*)&As[row * 32 + seg * 8] =
                    *(const uint4*)&A[(size_t)gr * K + k0 + seg * 8];
            }
        }
#pragma unroll
        for (int i = 0; i < BNt * 4 / 256; ++i) {
            const int s   = i * 256 + tid;
            const int row = s >> 2;
            const int seg = s & 3;
            *(uint4*)&Bs[row * 32 + seg * 8] =
                *(const uint4*)&BT[(size_t)row * K + k0 + seg * 8];
        }
        __syncthreads();

        short8 af[WMF], bfr[WNF];
#pragma unroll
        for (int i = 0; i < WMF; ++i)
            af[i] = *(const short8*)&As[(wm + i * 16 + fm) * 32 + kh * 8];
#pragma unroll
        for (int j = 0; j < WNF; ++j)
            bfr[j] = *(const short8*)&Bs[(wn + j * 16 + fm) * 32 + kh * 8];
#pragma unroll
        for (int i = 0; i < WMF; ++i)
#pragma unroll
            for (int j = 0; j < WNF; ++j)
                acc[i][j] = __builtin_amdgcn_mfma_f32_16x16x32_bf16(
                    af[i], bfr[j], acc[i][j], 0, 0, 0);
    }

#pragma unroll
    for (int i = 0; i < WMF; ++i) {
#pragma unroll
        for (int j = 0; j < WNF; ++j) {
            const int col = wn + j * 16 + fm;
#pragma unroll
            for (int r = 0; r < 4; ++r) {
                const int row = m0 + wm + i * 16 + kh * 4 + r;
                if (row < M) C[(size_t)row * BNt + col] = f2bf(acc[i][j][r]);
            }
        }
    }
}

__global__ __launch_bounds__(256) void gemm2_k(
    const float* __restrict__ A, const u16* __restrict__ BT,
    u16* __restrict__ C, int M, int K)
{
    gemm_body<float, 64>(blockIdx.x, A, BT, C, M, K);
}

// ---------------- sort pass A1: per-block coarse histogram (+ weight tc) ----
__global__ __launch_bounds__(256) void sortA1_k(
    const int* __restrict__ dst, int* __restrict__ G, int E, int NBLK, int NB,
    const float* __restrict__ W1, u16* __restrict__ W1T, int K1, int N1,
    const float* __restrict__ W2, u16* __restrict__ W2T, int K2, int N2)
{
    const int b = blockIdx.x;
    if (b >= NBLK) {
        // weight transpose/cast role
        const int t = (b - NBLK) * 256 + threadIdx.x;
        const int tot1 = K1 * N1;
        if (t < tot1) {
            const int k = t % K1, nn = t / K1;
            W1T[(size_t)nn * K1 + k] = f2bf(W1[(size_t)k * N1 + nn]);
        } else {
            const int t2 = t - tot1;
            if (t2 < K2 * N2) {
                const int k = t2 % K2, nn = t2 / K2;
                W2T[(size_t)nn * K2 + k] = f2bf(W2[(size_t)k * N2 + nn]);
            }
        }
        return;
    }

    __shared__ int hist[512];
    for (int i = threadIdx.x; i < NB; i += 256) hist[i] = 0;
    __syncthreads();
    const int base = b * TILE_A;
#pragma unroll 4
    for (int i = 0; i < TILE_A; i += 256) {
        const int e = base + i + threadIdx.x;
        if (e < E) atomicAdd(&hist[((unsigned)dst[e]) >> 8], 1);
    }
    __syncthreads();
    for (int i = threadIdx.x; i < NB; i += 256)
        G[(size_t)i * NBLK + b] = hist[i];
}

// ---------------- scans (over flat G, length NB*NBLK) ----------------

#define SCAN_B 256
#define SCAN_I 8
#define SCAN_TILE (SCAN_B * SCAN_I)   // 2048

__global__ __launch_bounds__(SCAN_B) void scan_pass1(
    const int* __restrict__ in, int* __restrict__ out,
    int* __restrict__ blockSums, int n)
{
    __shared__ int waveSums[SCAN_B / 64];
    const int tid = threadIdx.x;
    const int lane = tid & 63;
    const int wid = tid >> 6;
    const int base = blockIdx.x * SCAN_TILE + tid * SCAN_I;

    int items[SCAN_I];
    int tsum = 0;
#pragma unroll
    for (int i = 0; i < SCAN_I; ++i) {
        const int idx = base + i;
        items[i] = (idx < n) ? in[idx] : 0;
        tsum += items[i];
    }
    int x = tsum;
#pragma unroll
    for (int o = 1; o < 64; o <<= 1) {
        const int y = __shfl_up(x, o, 64);
        if (lane >= o) x += y;
    }
    if (lane == 63) waveSums[wid] = x;
    __syncthreads();
    if (tid == 0) {
        int acc = 0;
#pragma unroll
        for (int w = 0; w < SCAN_B / 64; ++w) {
            const int t = waveSums[w]; waveSums[w] = acc; acc += t;
        }
        blockSums[blockIdx.x] = acc;
    }
    __syncthreads();
    int texcl = x - tsum + waveSums[wid];
#pragma unroll
    for (int i = 0; i < SCAN_I; ++i) {
        const int idx = base + i;
        if (idx < n) out[idx] = texcl;
        texcl += items[i];
    }
}

__global__ void scan_pass2(int* __restrict__ blockSums, int nb)
{
    const int lane = threadIdx.x;
    int run = 0;
    for (int base = 0; base < nb; base += 64) {
        const int idx = base + lane;
        const int v = (idx < nb) ? blockSums[idx] : 0;
        int x = v;
#pragma unroll
        for (int o = 1; o < 64; o <<= 1) {
            const int y = __shfl_up(x, o, 64);
            if (lane >= o) x += y;
        }
        if (idx < nb) blockSums[idx] = run + x - v;
        run += __shfl(x, 63, 64);
    }
}

__global__ __launch_bounds__(SCAN_B) void scan3G_k(
    int* __restrict__ G, const int* __restrict__ blockSums, int n,
    int* __restrict__ offs, int N, int E)
{
    const int idx = blockIdx.x * blockDim.x + threadIdx.x;
    if (idx < n) G[idx] += blockSums[idx / SCAN_TILE];
    if (idx == 0) offs[N] = E;
}

// ---------------- sort pass A2: place into bucket-grouped scratch ----------
__global__ __launch_bounds__(256) void sortA2_k(
    const int* __restrict__ src, const int* __restrict__ dst,
    const float* __restrict__ ew, const int* __restrict__ G,
    uint2* __restrict__ eps, u8* __restrict__ ldst, int E, int NBLK, int NB)
{
    const int b = blockIdx.x;
    __shared__ int cur[512];
    for (int i = threadIdx.x; i < NB; i += 256)
        cur[i] = G[(size_t)i * NBLK + b];
    __syncthreads();
    const int base = b * TILE_A;
#pragma unroll 4
    for (int i = 0; i < TILE_A; i += 256) {
        const int e = base + i + threadIdx.x;
        if (e < E) {
            const int d = dst[e];
            const int p = atomicAdd(&cur[((unsigned)d) >> 8], 1);
            eps[p]  = make_uint2((unsigned)src[e], fau(ew[e]));
            ldst[p] = (u8)(d & 255);
        }
    }
}

// ---------------- megaB: per-bucket exact sort || gemm1 ---------------------
// Block roles: b%3==0 && b/3<SB -> sort bucket b/3; else gemm1 block.
__global__ __launch_bounds__(256) void megaB_k(
    const uint2* __restrict__ eps, const u8* __restrict__ ldst,
    const int* __restrict__ G, int* __restrict__ offs,
    uint2* __restrict__ epack, int E, int NBLK, int NB, int N,
    const float* __restrict__ A, const u16* __restrict__ BT,
    u16* __restrict__ C, int M, int K, int GB)
{
    const int b = blockIdx.x;
    const int third = b / 3;
    int sort_id = -1, gemm_id = -1;
    if ((b % 3) == 0 && third < NB) sort_id = third;
    else gemm_id = b - min((b + 2) / 3, NB);

    if (gemm_id >= 0) {
        if (gemm_id < GB) gemm_body<float, 128>(gemm_id, A, BT, C, M, K);
        return;
    }

    const int tid = threadIdx.x;
    const int sb = sort_id;
    const int start = G[(size_t)sb * NBLK];
    const int endv  = (sb + 1 < NB) ? G[(size_t)(sb + 1) * NBLK] : E;

    __shared__ int h[256];
    __shared__ int wsum[4];
    h[tid] = 0;
    __syncthreads();
    for (int i = start + tid; i < endv; i += 256)
        atomicAdd(&h[ldst[i]], 1);
    __syncthreads();

    // 256-entry exclusive scan (wave shfl + 4-way combine)
    const int lane = tid & 63;
    const int w = tid >> 6;
    const int v = h[tid];
    int x = v;
#pragma unroll
    for (int o = 1; o < 64; o <<= 1) {
        const int y = __shfl_up(x, o, 64);
        if (lane >= o) x += y;
    }
    if (lane == 63) wsum[w] = x;
    __syncthreads();
    if (tid == 0) {
        int a = 0;
#pragma unroll
        for (int q = 0; q < 4; ++q) { const int t = wsum[q]; wsum[q] = a; a += t; }
    }
    __syncthreads();
    const int excl = start + (x - v) + wsum[w];

    const int node = sb * 256 + tid;
    if (node < N) offs[node] = excl;

    __syncthreads();
    h[tid] = excl;          // reuse as per-node cursor
    __syncthreads();

    for (int i = start + tid; i < endv; i += 256) {
        const uint2 ep = eps[i];
        const int p = atomicAdd(&h[ldst[i]], 1);
        epack[p] = ep;
    }
}

// ---------------- gather-side aggregation (bf16 payload) ----------------
// 4 nodes per wave: 16 lanes per node, 16B (8 bf16) per lane.
// Fully-masked 8-wide edge loop (best measured). Out-of-range slots clamp to
// end-1 (cache-hit duplicate row) with weight=0 (exact no-op in fp32
// accumulation). Normal stores only (nt-stores caused flaky stale readback
// vs the harness's L2-resident d_out poison -- R5 failure).

__global__ __launch_bounds__(256) void agg_f128b(
    const u16* __restrict__ sup, const int* __restrict__ offs,
    const uint2* __restrict__ epack, const float* __restrict__ bias,
    float* __restrict__ out, int N)
{
    const int node = (blockIdx.x * blockDim.x + threadIdx.x) >> 4;
    const int hl = threadIdx.x & 15;
    if (node >= N) return;

    const int beg = offs[node];
    const int end = offs[node + 1];

    float a[2][8] = {};
    for (int j = beg; j < end; j += 8) {
        uint2 e[8];
#pragma unroll
        for (int i = 0; i < 8; ++i) {
            const int jj = (j + i < end) ? (j + i) : (end - 1);
            e[i] = epack[jj];
        }
#pragma unroll
        for (int i = 0; i < 8; ++i)
            if (j + i >= end) e[i].y = 0u;     // weight = 0.0f for masked slots
        uint4 v[8];
#pragma unroll
        for (int i = 0; i < 8; ++i)
            v[i] = *(const uint4*)&sup[(size_t)e[i].x * 128 + hl * 8];
#pragma unroll
        for (int i = 0; i < 8; ++i) {
            const float w = uaf(e[i].y);
            float* acc = a[i & 1];
            acc[0] = fmaf(bf2f(v[i].x & 0xffffu), w, acc[0]);
            acc[1] = fmaf(bf2f(v[i].x >> 16),     w, acc[1]);
            acc[2] = fmaf(bf2f(v[i].y & 0xffffu), w, acc[2]);
            acc[3] = fmaf(bf2f(v[i].y >> 16),     w, acc[3]);
            acc[4] = fmaf(bf2f(v[i].z & 0xffffu), w, acc[4]);
            acc[5] = fmaf(bf2f(v[i].z >> 16),     w, acc[5]);
            acc[6] = fmaf(bf2f(v[i].w & 0xffffu), w, acc[6]);
            acc[7] = fmaf(bf2f(v[i].w >> 16),     w, acc[7]);
        }
    }
    const float4 b0 = *(const float4*)&bias[hl * 8];
    const float4 b1 = *(const float4*)&bias[hl * 8 + 4];
    float4v o0, o1;
    o0[0] = fmaxf(a[0][0] + a[1][0] + b0.x, 0.f);
    o0[1] = fmaxf(a[0][1] + a[1][1] + b0.y, 0.f);
    o0[2] = fmaxf(a[0][2] + a[1][2] + b0.z, 0.f);
    o0[3] = fmaxf(a[0][3] + a[1][3] + b0.w, 0.f);
    o1[0] = fmaxf(a[0][4] + a[1][4] + b1.x, 0.f);
    o1[1] = fmaxf(a[0][5] + a[1][5] + b1.y, 0.f);
    o1[2] = fmaxf(a[0][6] + a[1][6] + b1.z, 0.f);
    o1[3] = fmaxf(a[0][7] + a[1][7] + b1.w, 0.f);
    float4v* orow = (float4v*)&out[(size_t)node * 128 + hl * 8];
    orow[0] = o0;
    orow[1] = o1;
}

__global__ __launch_bounds__(256) void agg_f64_lsm(
    const u16* __restrict__ sup, const int* __restrict__ offs,
    const uint2* __restrict__ epack, const float* __restrict__ bias,
    float* __restrict__ out, int N)
{
    const int node = (blockIdx.x * blockDim.x + threadIdx.x) >> 4;
    const int hl = threadIdx.x & 15;
    if (node >= N) return;

    const int beg = offs[node];
    const int end = offs[node + 1];

    float a[2][4] = {};
    for (int j = beg; j < end; j += 8) {
        uint2 e[8];
#pragma unroll
        for (int i = 0; i < 8; ++i) {
            const int jj = (j + i < end) ? (j + i) : (end - 1);
            e[i] = epack[jj];
        }
#pragma unroll
        for (int i = 0; i < 8; ++i)
            if (j + i >= end) e[i].y = 0u;     // weight = 0.0f for masked slots
        uint2 v[8];
#pragma unroll
        for (int i = 0; i < 8; ++i)
            v[i] = *(const uint2*)&sup[(size_t)e[i].x * 64 + hl * 4];
#pragma unroll
        for (int i = 0; i < 8; ++i) {
            const float w = uaf(e[i].y);
            float* acc = a[i & 1];
            acc[0] = fmaf(bf2f(v[i].x & 0xffffu), w, acc[0]);
            acc[1] = fmaf(bf2f(v[i].x >> 16),     w, acc[1]);
            acc[2] = fmaf(bf2f(v[i].y & 0xffffu), w, acc[2]);
            acc[3] = fmaf(bf2f(v[i].y >> 16),     w, acc[3]);
        }
    }

    const float4 b4 = *(const float4*)&bias[hl * 4];
    float z[4];
    z[0] = a[0][0] + a[1][0] + b4.x;
    z[1] = a[0][1] + a[1][1] + b4.y;
    z[2] = a[0][2] + a[1][2] + b4.z;
    z[3] = a[0][3] + a[1][3] + b4.w;

    float m = fmaxf(fmaxf(z[0], z[1]), fmaxf(z[2], z[3]));
#pragma unroll
    for (int o = 8; o > 0; o >>= 1) m = fmaxf(m, __shfl_xor(m, o, 64));
    float s = __expf(z[0] - m) + __expf(z[1] - m) + __expf(z[2] - m) + __expf(z[3] - m);
#pragma unroll
    for (int o = 8; o > 0; o >>= 1) s += __shfl_xor(s, o, 64);
    const float ls = __logf(s);
    *(float4*)&out[(size_t)node * 64 + hl * 4] =
        make_float4(z[0] - m - ls, z[1] - m - ls, z[2] - m - ls, z[3] - m - ls);
}

// ---------------------------------------------------------------------------

extern "C" void kernel_launch(void* const* d_in, const int* in_sizes, int n_in,
                              void* d_out, int out_size, void* d_ws, size_t ws_size,
                              hipStream_t stream) {
    const float* feature = (const float*)d_in[0];
    const int*   src     = (const int*)d_in[1];
    const int*   dst     = (const int*)d_in[2];
    const float* ew      = (const float*)d_in[3];
    const float* W1      = (const float*)d_in[4];
    const float* b1      = (const float*)d_in[5];
    const float* W2      = (const float*)d_in[6];
    const float* b2      = (const float*)d_in[7];

    const int E    = in_sizes[1];
    const int H    = in_sizes[5];            // 128
    const int D    = in_sizes[7];            // 64
    const int F_IN = in_sizes[4] / H;        // 256
    const int N    = in_sizes[0] / F_IN;     // 100000

    float* out_x1 = (float*)d_out;                   // [N, H] fp32
    float* out_x2 = (float*)d_out + (size_t)N * H;   // [N, D] fp32

    const int NB   = (N + 255) >> 8;         // coarse buckets (391)
    const int NBLK = (E + TILE_A - 1) / TILE_A;  // A-blocks (196)
    const int nG   = NB * NBLK;              // flat G length
    const int GB   = (N + 127) / 128;        // gemm1 blocks

    char* ws = (char*)d_ws;
    auto carve = [&](size_t bytes) {
        char* p = ws;
        ws += (bytes + 15) & ~(size_t)15;
        return p;
    };
    int*   G         = (int*)  carve((size_t)nG * sizeof(int));
    int*   blockSums = (int*)  carve(4096 * sizeof(int));
    int*   offs      = (int*)  carve((size_t)(N + 1) * sizeof(int));
    uint2* epack     = (uint2*)carve((size_t)E * sizeof(uint2));
    u16*   W1T       = (u16*)  carve((size_t)H * F_IN * sizeof(u16));
    u16*   W2T       = (u16*)  carve((size_t)D * H * sizeof(u16));
    u16*   supbf     = (u16*)  carve((size_t)N * H * sizeof(u16));
    u16*   scratch   = (u16*)  carve((size_t)N * H * sizeof(u16));
    // eps/ldst scratch (dead before agg_f128b runs):
    // need E*8 + E <= N*H*2  (14.4MB <= 25.6MB) -- holds.
    uint2* eps  = (uint2*)scratch;
    u8*    ldst = (u8*)scratch + (size_t)E * sizeof(uint2);

    // --- A1: coarse histogram + weight transposes ---
    {
        const int TCB = (F_IN * H + H * D + 255) / 256;
        sortA1_k<<<NBLK + TCB, 256, 0, stream>>>(
            dst, G, E, NBLK, NB, W1, W1T, F_IN, H, W2, W2T, H, D);
    }

    // --- scan of G (flat, bucket-major) ---
    const int nScanBlocks = (nG + SCAN_TILE - 1) / SCAN_TILE;
    scan_pass1<<<nScanBlocks, SCAN_B, 0, stream>>>(G, G, blockSums, nG);
    scan_pass2<<<1, 64, 0, stream>>>(blockSums, nScanBlocks);
    scan3G_k<<<(nG + SCAN_B - 1) / SCAN_B, SCAN_B, 0, stream>>>(
        G, blockSums, nG, offs, N, E);

    // --- A2: dense bucket-grouped placement ---
    sortA2_k<<<NBLK, 256, 0, stream>>>(src, dst, ew, G, eps, ldst, E, NBLK, NB);

    // --- megaB: per-bucket exact sort || gemm1 ---
    {
        int grid = NB + GB;
        if (grid < 3 * NB - 2) grid = 3 * NB - 2;   // ensure all sort blocks exist
        megaB_k<<<grid, 256, 0, stream>>>(
            eps, ldst, G, offs, epack, E, NBLK, NB, N,
            feature, W1T, supbf, N, F_IN, GB);
    }

    // --- agg layer 1 (fused bias+relu, fp32 out) ---
    agg_f128b<<<(N * 16 + 255) / 256, 256, 0, stream>>>(
        supbf, offs, epack, b1, out_x1, N);

    // --- layer 2 (gemm2 reads fp32 out_x1 directly) ---
    gemm2_k<<<(N + 127) / 128, 256, 0, stream>>>(out_x1, W2T, supbf, N, H);
    agg_f64_lsm<<<(N * 16 + 255) / 256, 256, 0, stream>>>(
        supbf, offs, epack, b2, out_x2, N);
}